// Round 13
// baseline (327.204 us; speedup 1.0000x reference)
//
#include <hip/hip_runtime.h>

#define D_MODEL 384
#define D_STATE 16
#define D_INNER 768
#define DT_RANK 24
#define NB 8
#define LSEQ 1024
#define NROWS (NB * LSEQ)             // 8192
#define DBC_N 56
#define SEG 16
#define NSEG 64

typedef unsigned short u16;
typedef __attribute__((ext_vector_type(8))) short bf16x8;
typedef __attribute__((ext_vector_type(4))) float f32x4;

__device__ __forceinline__ float silu(float x) { return x / (1.f + __expf(-x)); }

__device__ __forceinline__ u16 f2bf_rne(float v, float& hval) {
    unsigned u = __builtin_bit_cast(unsigned, v);
    unsigned h = (u + 0x7FFFu + ((u >> 16) & 1u)) >> 16;
    hval = __builtin_bit_cast(float, h << 16);
    return (u16)h;
}

__device__ __forceinline__ void split2(float v, u16& h, u16& l) {
    float hval, dummy;
    h = f2bf_rne(v, hval);
    l = f2bf_rne(v - hval, dummy);
}

// async global->LDS, 16B per lane (dest must be wave-uniform base + lane*16)
__device__ __forceinline__ void gload16(const u16* g, u16* l) {
    __builtin_amdgcn_global_load_lds(
        (const __attribute__((address_space(1))) unsigned int*)g,
        (__attribute__((address_space(3))) unsigned int*)l, 16, 0, 0);
}

// DPP move within rows of 16 lanes (VALU, no DS pipe). CTRL 0x120+N = row_ror:N.
template <int CTRL>
__device__ __forceinline__ float dpp_mov(float v) {
    return __builtin_bit_cast(float, __builtin_amdgcn_update_dpp(
        0, __builtin_bit_cast(int, v), CTRL, 0xf, 0xf, false));
}

// ---------------- merged weight split: in_proj + out_proj + x_proj(padded 56->64)
__global__ __launch_bounds__(256) void k_splits(const float* __restrict__ Wi,
                                                const float* __restrict__ Wo,
                                                const float* __restrict__ Wx,
                                                u16* __restrict__ Wi_hi, u16* __restrict__ Wi_lo,
                                                u16* __restrict__ Wo_hi, u16* __restrict__ Wo_lo,
                                                u16* __restrict__ Wx_hi, u16* __restrict__ Wx_lo) {
    const int NWi = 1536 * 384, NWo = 384 * 768, NWx = 64 * 768;
    const int i = blockIdx.x * 256 + threadIdx.x;
    if (i < NWi) {
        u16 h, l; split2(Wi[i], h, l);
        Wi_hi[i] = h; Wi_lo[i] = l;
    } else if (i < NWi + NWo) {
        const int j = i - NWi;
        u16 h, l; split2(Wo[j], h, l);
        Wo_hi[j] = h; Wo_lo[j] = l;
    } else if (i < NWi + NWo + NWx) {
        const int j = i - NWi - NWo;
        const int row = j / 768;
        u16 h = 0, l = 0;
        if (row < DBC_N) split2(Wx[j], h, l);
        Wx_hi[j] = h; Wx_lo[j] = l;
    }
}

// ---------------- activation split + transpose: src [B][R][1024] f32 -> hi/lo [B*1024][R] bf16
__global__ __launch_bounds__(256) void k_splitT(const float* __restrict__ src,
                                                u16* __restrict__ hi, u16* __restrict__ lo,
                                                int R) {
    __shared__ float s[32][33];
    const int r0 = blockIdx.x * 32, c0 = blockIdx.y * 32, b = blockIdx.z;
    const int t = threadIdx.x;
    const int cc = t & 31, rr = t >> 5;
#pragma unroll
    for (int p = 0; p < 4; ++p)
        s[rr + p * 8][cc] = src[((size_t)b * R + r0 + rr + p * 8) * LSEQ + c0 + cc];
    __syncthreads();
    const int rr2 = t & 31, cc2 = t >> 5;
#pragma unroll
    for (int p = 0; p < 4; ++p) {
        const int c = cc2 + p * 8;
        u16 h, l;
        split2(s[rr2][c], h, l);
        const size_t idx = ((size_t)b * LSEQ + c0 + c) * R + r0 + rr2;
        hi[idx] = h; lo[idx] = l;
    }
}

// ---------------- split-bf16 MFMA GEMM (128x128 tile), 16x16x32, k-tile outer / 3-term inner.
// global_load_lds staging, single barrier per k-tile.
template <int K>
__global__ __launch_bounds__(256) void k_gemm(const u16* __restrict__ Ahi,
                                              const u16* __restrict__ Alo,
                                              const u16* __restrict__ Bhi,
                                              const u16* __restrict__ Blo,
                                              float* __restrict__ out0,
                                              float* __restrict__ out1) {
    constexpr int KT = K / 32;
    __shared__ u16 lA[2][2][512 * 8];   // [dbuf][hi/lo]; index = (kchunk*128 + row)*8
    __shared__ u16 lB[2][2][512 * 8];
    const int tid = threadIdx.x;
    const int n0 = blockIdx.x * 128;
    const int m0 = blockIdx.y * 128;

    auto stage = [&](int kt, int buf) {
        const int ko = kt * 32;
#pragma unroll
        for (int i = 0; i < 2; ++i) {
            const int slot = tid + 256 * i;
            const size_t aoff = (size_t)(m0 + (slot & 127)) * K + ko + (slot >> 7) * 8;
            const size_t boff = (size_t)(n0 + (slot & 127)) * K + ko + (slot >> 7) * 8;
            gload16(Ahi + aoff, &lA[buf][0][slot * 8]);
            gload16(Alo + aoff, &lA[buf][1][slot * 8]);
            gload16(Bhi + boff, &lB[buf][0][slot * 8]);
            gload16(Blo + boff, &lB[buf][1][slot * 8]);
        }
    };

    stage(0, 0);
    __syncthreads();

    const int lane = tid & 63, w = tid >> 6;
    const int wm = w >> 1, wn = w & 1;
    const int fr = lane & 15, g = lane >> 4;
    const int abase = (g * 128 + wm * 64 + fr) * 8;
    const int bbase = (g * 128 + wn * 64 + fr) * 8;

    f32x4 acc[4][4] = {};
    for (int kt = 0; kt < KT; ++kt) {
        const int cur = kt & 1;
        if (kt + 1 < KT) stage(kt + 1, cur ^ 1);
        bf16x8 ah[4], al[4], bh[4], bl[4];
#pragma unroll
        for (int mi = 0; mi < 4; ++mi) {
            ah[mi] = *reinterpret_cast<const bf16x8*>(&lA[cur][0][abase + mi * 128]);
            al[mi] = *reinterpret_cast<const bf16x8*>(&lA[cur][1][abase + mi * 128]);
        }
#pragma unroll
        for (int ni = 0; ni < 4; ++ni) {
            bh[ni] = *reinterpret_cast<const bf16x8*>(&lB[cur][0][bbase + ni * 128]);
            bl[ni] = *reinterpret_cast<const bf16x8*>(&lB[cur][1][bbase + ni * 128]);
        }
#pragma unroll
        for (int mi = 0; mi < 4; ++mi)
#pragma unroll
            for (int ni = 0; ni < 4; ++ni) {
                acc[mi][ni] = __builtin_amdgcn_mfma_f32_16x16x32_bf16(
                    ah[mi], bh[ni], acc[mi][ni], 0, 0, 0);
                acc[mi][ni] = __builtin_amdgcn_mfma_f32_16x16x32_bf16(
                    ah[mi], bl[ni], acc[mi][ni], 0, 0, 0);
                acc[mi][ni] = __builtin_amdgcn_mfma_f32_16x16x32_bf16(
                    al[mi], bh[ni], acc[mi][ni], 0, 0, 0);
            }
        __syncthreads();
    }

    const int b_idx = m0 >> 10;
    const int l0b = m0 & 1023;
    if (n0 < D_INNER) {
#pragma unroll
        for (int mi = 0; mi < 4; ++mi) {
#pragma unroll
            for (int ni = 0; ni < 4; ++ni) {
                const int m = m0 + wm * 64 + mi * 16 + g * 4;
                const int nn = n0 + wn * 64 + ni * 16 + fr;
#pragma unroll
                for (int j = 0; j < 4; ++j)
                    out0[(size_t)(m + j) * D_INNER + nn] = acc[mi][ni][j];
            }
        }
    } else {
#pragma unroll
        for (int mi = 0; mi < 4; ++mi) {
#pragma unroll
            for (int ni = 0; ni < 4; ++ni) {
                const int l = l0b + wm * 64 + mi * 16 + g * 4;
                const int dd = (n0 - D_INNER) + wn * 64 + ni * 16 + fr;
                float4 v = make_float4(silu(acc[mi][ni][0]), silu(acc[mi][ni][1]),
                                       silu(acc[mi][ni][2]), silu(acc[mi][ni][3]));
                *reinterpret_cast<float4*>(
                    &out1[((size_t)b_idx * D_INNER + dd) * LSEQ + l]) = v;
            }
        }
    }
}

// ---------------- out_proj GEMM: 128m x 64n tile, K=768, global_load_lds staging.
__global__ __launch_bounds__(256) void k_gemmo(const u16* __restrict__ Ahi,
                                               const u16* __restrict__ Alo,
                                               const u16* __restrict__ Bhi,
                                               const u16* __restrict__ Blo,
                                               float* __restrict__ out) {
    constexpr int KT = 24;
    __shared__ u16 lA[2][2][512 * 8];   // 128 rows: (kc*128+row)*8
    __shared__ u16 lB[2][2][256 * 8];   // 64 rows:  (kc*64+row)*8
    const int tid = threadIdx.x;
    const int n0 = blockIdx.x * 64;
    const int m0 = blockIdx.y * 128;

    auto stage = [&](int kt, int buf) {
        const int ko = kt * 32;
#pragma unroll
        for (int i = 0; i < 2; ++i) {
            const int slot = tid + 256 * i;
            const size_t aoff = (size_t)(m0 + (slot & 127)) * D_INNER + ko + (slot >> 7) * 8;
            gload16(Ahi + aoff, &lA[buf][0][slot * 8]);
            gload16(Alo + aoff, &lA[buf][1][slot * 8]);
        }
        const size_t boff = (size_t)(n0 + (tid & 63)) * D_INNER + ko + (tid >> 6) * 8;
        gload16(Bhi + boff, &lB[buf][0][tid * 8]);
        gload16(Blo + boff, &lB[buf][1][tid * 8]);
    };

    stage(0, 0);
    __syncthreads();

    const int lane = tid & 63, w = tid >> 6;
    const int wm = w >> 1, wn = w & 1;
    const int fr = lane & 15, g = lane >> 4;
    const int abase = (g * 128 + wm * 64 + fr) * 8;
    const int bbase = (g * 64 + wn * 32 + fr) * 8;

    f32x4 acc[4][2] = {};
    for (int kt = 0; kt < KT; ++kt) {
        const int cur = kt & 1;
        if (kt + 1 < KT) stage(kt + 1, cur ^ 1);
        bf16x8 ah[4], al[4], bh[2], bl[2];
#pragma unroll
        for (int mi = 0; mi < 4; ++mi) {
            ah[mi] = *reinterpret_cast<const bf16x8*>(&lA[cur][0][abase + mi * 128]);
            al[mi] = *reinterpret_cast<const bf16x8*>(&lA[cur][1][abase + mi * 128]);
        }
#pragma unroll
        for (int ni = 0; ni < 2; ++ni) {
            bh[ni] = *reinterpret_cast<const bf16x8*>(&lB[cur][0][bbase + ni * 128]);
            bl[ni] = *reinterpret_cast<const bf16x8*>(&lB[cur][1][bbase + ni * 128]);
        }
#pragma unroll
        for (int mi = 0; mi < 4; ++mi)
#pragma unroll
            for (int ni = 0; ni < 2; ++ni) {
                acc[mi][ni] = __builtin_amdgcn_mfma_f32_16x16x32_bf16(
                    ah[mi], bh[ni], acc[mi][ni], 0, 0, 0);
                acc[mi][ni] = __builtin_amdgcn_mfma_f32_16x16x32_bf16(
                    ah[mi], bl[ni], acc[mi][ni], 0, 0, 0);
                acc[mi][ni] = __builtin_amdgcn_mfma_f32_16x16x32_bf16(
                    al[mi], bh[ni], acc[mi][ni], 0, 0, 0);
            }
        __syncthreads();
    }

    const int b_idx = m0 >> 10;
    const int l0b = m0 & 1023;
#pragma unroll
    for (int mi = 0; mi < 4; ++mi) {
#pragma unroll
        for (int ni = 0; ni < 2; ++ni) {
            const int nn = n0 + wn * 32 + ni * 16 + fr;
            const int l = l0b + wm * 64 + mi * 16 + g * 4;
            float4 v = make_float4(acc[mi][ni][0], acc[mi][ni][1],
                                   acc[mi][ni][2], acc[mi][ni][3]);
            *reinterpret_cast<float4*>(
                &out[((size_t)b_idx * D_MODEL + nn) * LSEQ + l]) = v;
        }
    }
}

// ---------------- x_proj MFMA GEMM: 32-row m-tiles, N=64, K=768, global_load_lds staging.
__global__ __launch_bounds__(256) void k_xprojm(const u16* __restrict__ Uhi,
                                                const u16* __restrict__ Ulo,
                                                const u16* __restrict__ Whi,
                                                const u16* __restrict__ Wlo,
                                                float* __restrict__ dbc,
                                                float* __restrict__ bct) {
    __shared__ u16 lA[2][2][128 * 8];   // 32 rows: (kc*32+row)*8
    __shared__ u16 lB[2][2][256 * 8];   // 64 rows: (kc*64+row)*8
    const int tid = threadIdx.x;
    const int m0 = blockIdx.x * 32;

    auto stage = [&](int kt, int buf) {
        const int ko = kt * 32;
        if (tid < 128) {
            const size_t aoff = (size_t)(m0 + (tid & 31)) * D_INNER + ko + (tid >> 5) * 8;
            gload16(Uhi + aoff, &lA[buf][0][tid * 8]);
            gload16(Ulo + aoff, &lA[buf][1][tid * 8]);
        }
        const size_t boff = (size_t)(tid & 63) * D_INNER + ko + (tid >> 6) * 8;
        gload16(Whi + boff, &lB[buf][0][tid * 8]);
        gload16(Wlo + boff, &lB[buf][1][tid * 8]);
    };

    stage(0, 0);
    __syncthreads();

    const int lane = tid & 63, w = tid >> 6;
    const int fr = lane & 15, g = lane >> 4;
    f32x4 acc[2] = {};
    for (int kt = 0; kt < 24; ++kt) {
        const int cur = kt & 1;
        if (kt + 1 < 24) stage(kt + 1, cur ^ 1);
        bf16x8 ah[2], al[2];
#pragma unroll
        for (int mi = 0; mi < 2; ++mi) {
            const int af = (g * 32 + mi * 16 + fr) * 8;
            ah[mi] = *reinterpret_cast<const bf16x8*>(&lA[cur][0][af]);
            al[mi] = *reinterpret_cast<const bf16x8*>(&lA[cur][1][af]);
        }
        const int bf = (g * 64 + w * 16 + fr) * 8;
        bf16x8 bh = *reinterpret_cast<const bf16x8*>(&lB[cur][0][bf]);
        bf16x8 bl = *reinterpret_cast<const bf16x8*>(&lB[cur][1][bf]);
#pragma unroll
        for (int mi = 0; mi < 2; ++mi) {
            acc[mi] = __builtin_amdgcn_mfma_f32_16x16x32_bf16(ah[mi], bh, acc[mi], 0, 0, 0);
            acc[mi] = __builtin_amdgcn_mfma_f32_16x16x32_bf16(ah[mi], bl, acc[mi], 0, 0, 0);
            acc[mi] = __builtin_amdgcn_mfma_f32_16x16x32_bf16(al[mi], bh, acc[mi], 0, 0, 0);
        }
        __syncthreads();
    }

    const int b_idx = m0 >> 10;
    const int col = w * 16 + fr;
#pragma unroll
    for (int mi = 0; mi < 2; ++mi) {
#pragma unroll
        for (int j = 0; j < 4; ++j) {
            const int r = mi * 16 + g * 4 + j;
            const float v = acc[mi][j];
            if (col < DT_RANK) {
                dbc[(size_t)(m0 + r) * DBC_N + col] = v;
            } else if (col < DBC_N) {
                bct[((size_t)b_idx * 32 + (col - DT_RANK)) * LSEQ + ((m0 & 1023) + r)] = v;
            }
        }
    }
}

// ---------------- conv (causal, 3 taps) + SiLU -> uT [b][d][l] f32 + u split bf16 row-major
__global__ __launch_bounds__(256) void k_conv(const float* __restrict__ xin,
                                              const float* __restrict__ cw,
                                              const float* __restrict__ cb,
                                              u16* __restrict__ u_hi,
                                              u16* __restrict__ u_lo,
                                              float* __restrict__ uT) {
    __shared__ float xs[34][32];
    __shared__ float us[32][33];
    const int d0 = blockIdx.x * 32;
    const int l0 = blockIdx.y * 32;
    const int b  = blockIdx.z;
    const int t = threadIdx.x;
    const int dd = t & 31, r = t >> 5;
    for (int rr = r; rr < 34; rr += 8) {
        const int l = l0 - 2 + rr;
        xs[rr][dd] = (l >= 0) ? xin[((size_t)b * LSEQ + l) * D_INNER + d0 + dd] : 0.f;
    }
    __syncthreads();
    const float w0 = cw[(d0 + dd) * 3 + 0], w1 = cw[(d0 + dd) * 3 + 1], w2 = cw[(d0 + dd) * 3 + 2];
    const float bv = cb[d0 + dd];
#pragma unroll
    for (int p = 0; p < 4; ++p) {
        const int li = r + p * 8;
        float acc = bv;
        acc = fmaf(xs[li + 0][dd], w0, acc);
        acc = fmaf(xs[li + 1][dd], w1, acc);
        acc = fmaf(xs[li + 2][dd], w2, acc);
        const float uv = silu(acc);
        u16 h, l;
        split2(uv, h, l);
        const size_t idx = ((size_t)b * LSEQ + l0 + li) * D_INNER + d0 + dd;
        u_hi[idx] = h; u_lo[idx] = l;
        us[li][dd] = uv;
    }
    __syncthreads();
    const int ll = t & 31, dg = t >> 5;
#pragma unroll
    for (int p = 0; p < 4; ++p) {
        const int dl = dg + p * 8;
        uT[((size_t)b * D_INNER + d0 + dl) * LSEQ + l0 + ll] = us[ll][dl];
    }
}

// ---------------- dt_proj (K=24) + softplus -> dtT[b][d][l] (transposed via LDS tile)
__global__ __launch_bounds__(256) void k_dtproj(const float* __restrict__ dbc,
                                                const float* __restrict__ W,
                                                const float* __restrict__ bias,
                                                float* __restrict__ dtT) {
    __shared__ float sd[64][25];
    __shared__ float sw[64][24];
    __shared__ float sb[64];
    const int d0 = blockIdx.x * 64;
    const int row0 = blockIdx.y * 64;
    const int b = row0 >> 10, lr0 = row0 & 1023;
    const int t = threadIdx.x;
    for (int e = t; e < 64 * 24; e += 256) {
        const int rl = e / 24, rr = e - rl * 24;
        sd[rl][rr] = dbc[(size_t)(row0 + rl) * DBC_N + rr];
        sw[rl][rr] = W[(size_t)(d0 + rl) * DT_RANK + rr];
    }
    if (t < 64) sb[t] = bias[d0 + t];
    __syncthreads();
    const int ll = t & 63, dg = t >> 6;
    for (int dd = 0; dd < 16; ++dd) {
        const int dl = dg * 16 + dd;
        float acc = sb[dl];
#pragma unroll
        for (int r = 0; r < DT_RANK; ++r) acc = fmaf(sd[ll][r], sw[dl][r], acc);
        const float v = (acc > 20.f) ? acc : log1pf(__expf(acc));
        dtT[((size_t)b * D_INNER + d0 + dl) * LSEQ + lr0 + ll] = v;
    }
}

// ---------------- block-parallel selective scan v3c: chunked ds_read_b128 for dt/u
// (4 b128 per pass instead of 16 b32), chunked masked y/sz (b128), exp2 fold.
__global__ __launch_bounds__(1024, 8) void k_scan(float* dtyT,
                                                  const float* __restrict__ uT,
                                                  const float* __restrict__ szT,
                                                  const float* __restrict__ bct,
                                                  const float* __restrict__ A_log,
                                                  const float* __restrict__ Dp) {
    __shared__ float dt_s[LSEQ], u_s[LSEQ], sz_s[LSEQ], y_s[LSEQ];
    __shared__ float Pb[16][NSEG + 2], Hb[16][NSEG + 2];
    const int t = threadIdx.x;
    const int d = blockIdx.x;
    const int b = blockIdx.y;
    const size_t base = ((size_t)b * D_INNER + d) * LSEQ;
    if (t < 256) {
        *reinterpret_cast<float4*>(&dt_s[t * 4]) =
            *reinterpret_cast<const float4*>(&dtyT[base + t * 4]);
    } else if (t < 512) {
        const int q = (t - 256) * 4;
        *reinterpret_cast<float4*>(&u_s[q]) = *reinterpret_cast<const float4*>(&uT[base + q]);
    } else if (t < 768) {
        const int q = (t - 512) * 4;
        *reinterpret_cast<float4*>(&sz_s[q]) = *reinterpret_cast<const float4*>(&szT[base + q]);
    }
    const int n = t & 15, seg = t >> 4;
    const float Aval2 = -__expf(A_log[d * D_STATE + n]) * 1.44269504088896f;
    const float Dv = Dp[d];
    float Breg[SEG];
    {
        const size_t bb = ((size_t)b * 32 + n) * LSEQ + seg * SEG;
#pragma unroll
        for (int q = 0; q < SEG; q += 4)
            *reinterpret_cast<float4*>(&Breg[q]) = *reinterpret_cast<const float4*>(&bct[bb + q]);
    }
    __syncthreads();
    const int l0 = seg * SEG;
    // pass A: chunked b128 reads, running (P, H)
    float h = 0.f, P = 1.f;
#pragma unroll
    for (int j = 0; j < 4; ++j) {
        const float4 dt4 = *reinterpret_cast<const float4*>(&dt_s[l0 + j * 4]);
        const float4 u4  = *reinterpret_cast<const float4*>(&u_s[l0 + j * 4]);
        float a;
        a = exp2f(dt4.x * Aval2); h = fmaf(a, h, dt4.x * u4.x * Breg[j * 4 + 0]); P *= a;
        a = exp2f(dt4.y * Aval2); h = fmaf(a, h, dt4.y * u4.y * Breg[j * 4 + 1]); P *= a;
        a = exp2f(dt4.z * Aval2); h = fmaf(a, h, dt4.z * u4.z * Breg[j * 4 + 2]); P *= a;
        a = exp2f(dt4.w * Aval2); h = fmaf(a, h, dt4.w * u4.w * Breg[j * 4 + 3]); P *= a;
    }
    Pb[n][seg] = P;
    Hb[n][seg] = h;
    // deferred Creg load: latency hides under the scan phase below
    float Creg[SEG];
    {
        const size_t cc = ((size_t)b * 32 + 16 + n) * LSEQ + seg * SEG;
#pragma unroll
        for (int q = 0; q < SEG; q += 4)
            *reinterpret_cast<float4*>(&Creg[q]) = *reinterpret_cast<const float4*>(&bct[cc + q]);
    }
    __syncthreads();
    // in-wave inclusive scan: wave w owns state n=w, lane = segment index
    {
        const int w = t >> 6, lane = t & 63;
        float Pw = Pb[w][lane], Hw = Hb[w][lane];
#pragma unroll
        for (int off = 1; off < NSEG; off <<= 1) {
            const float Pp = __shfl_up(Pw, off);
            const float Hp = __shfl_up(Hw, off);
            if (lane >= off) {
                Hw = fmaf(Hp, Pw, Hw);
                Pw *= Pp;
            }
        }
        Hb[w][lane] = Hw;
    }
    __syncthreads();
    // pass C: chunked; per-step DPP rotate-reduce; masked chunked y store
    h = (seg == 0) ? 0.f : Hb[n][seg - 1];
#pragma unroll
    for (int j = 0; j < 4; ++j) {
        const float4 dt4 = *reinterpret_cast<const float4*>(&dt_s[l0 + j * 4]);
        const float4 u4  = *reinterpret_cast<const float4*>(&u_s[l0 + j * 4]);
        float a, p, y0, y1, y2, y3;
        a = exp2f(dt4.x * Aval2); h = fmaf(a, h, dt4.x * u4.x * Breg[j * 4 + 0]);
        p = h * Creg[j * 4 + 0];
        p += dpp_mov<0x128>(p); p += dpp_mov<0x124>(p);
        p += dpp_mov<0x122>(p); p += dpp_mov<0x121>(p);
        y0 = p;
        a = exp2f(dt4.y * Aval2); h = fmaf(a, h, dt4.y * u4.y * Breg[j * 4 + 1]);
        p = h * Creg[j * 4 + 1];
        p += dpp_mov<0x128>(p); p += dpp_mov<0x124>(p);
        p += dpp_mov<0x122>(p); p += dpp_mov<0x121>(p);
        y1 = p;
        a = exp2f(dt4.z * Aval2); h = fmaf(a, h, dt4.z * u4.z * Breg[j * 4 + 2]);
        p = h * Creg[j * 4 + 2];
        p += dpp_mov<0x128>(p); p += dpp_mov<0x124>(p);
        p += dpp_mov<0x122>(p); p += dpp_mov<0x121>(p);
        y2 = p;
        a = exp2f(dt4.w * Aval2); h = fmaf(a, h, dt4.w * u4.w * Breg[j * 4 + 3]);
        p = h * Creg[j * 4 + 3];
        p += dpp_mov<0x128>(p); p += dpp_mov<0x124>(p);
        p += dpp_mov<0x122>(p); p += dpp_mov<0x121>(p);
        y3 = p;
        if (n == 0) {
            const float4 sz4 = *reinterpret_cast<const float4*>(&sz_s[l0 + j * 4]);
            float4 yy;
            yy.x = fmaf(u4.x, Dv, y0) * sz4.x;
            yy.y = fmaf(u4.y, Dv, y1) * sz4.y;
            yy.z = fmaf(u4.z, Dv, y2) * sz4.z;
            yy.w = fmaf(u4.w, Dv, y3) * sz4.w;
            *reinterpret_cast<float4*>(&y_s[l0 + j * 4]) = yy;
        }
    }
    __syncthreads();
    if (t < 256)
        *reinterpret_cast<float4*>(&dtyT[base + t * 4]) =
            *reinterpret_cast<const float4*>(&y_s[t * 4]);
}

extern "C" void kernel_launch(void* const* d_in, const int* in_sizes, int n_in,
                              void* d_out, int out_size, void* d_ws, size_t ws_size,
                              hipStream_t stream) {
    const float* x         = (const float*)d_in[0];
    const float* in_proj_w = (const float*)d_in[1];
    const float* conv_w    = (const float*)d_in[2];
    const float* conv_b    = (const float*)d_in[3];
    const float* x_proj_w  = (const float*)d_in[4];
    const float* dt_proj_w = (const float*)d_in[5];
    const float* dt_proj_b = (const float*)d_in[6];
    const float* A_log     = (const float*)d_in[7];
    const float* Dp        = (const float*)d_in[8];
    const float* out_proj_w= (const float*)d_in[9];
    float* out = (float*)d_out;

    const size_t SB = (size_t)NROWS * D_INNER * 4;   // 25.2 MB
    char* wsb = (char*)d_ws;
    float* xin   = (float*)(wsb);                    // R0: xin, then dtT/y
    float* szT   = (float*)(wsb + SB);               // R1
    u16*  u_hi   = (u16*)  (wsb + 2 * SB);           // R2: u split bf16
    u16*  u_lo   = u_hi + (size_t)NROWS * D_INNER;
    float* uT    = (float*)(wsb + 3 * SB);           // R3: Ax split, then uT, then Ay split
    float* dbc   = (float*)(wsb + 4 * SB);
    float* bct   = (float*)(wsb + 4 * SB + 1835008);
    u16*  Wi_hi  = (u16*) (wsb + 4 * SB + 1835008 + 1048576);
    u16*  Wi_lo  = Wi_hi + 1536 * 384;
    u16*  Wo_hi  = Wi_lo + 1536 * 384;
    u16*  Wo_lo  = Wo_hi + 384 * 768;
    u16*  Wx_hi  = Wo_lo + 384 * 768;
    u16*  Wx_lo  = Wx_hi + 64 * 768;
    u16*  Ax_hi  = (u16*)uT;                 // dead before conv writes uT
    u16*  Ax_lo  = Ax_hi + (size_t)NROWS * 384;
    u16*  Ay_hi  = (u16*)uT;                 // uT dead after scan
    u16*  Ay_lo  = Ay_hi + (size_t)NROWS * 768;
    float* dtyT  = xin;                      // xin dead after conv; dt then y in place

    const int NSPLIT = 1536 * 384 + 384 * 768 + 64 * 768;
    k_splits<<<(NSPLIT + 255) / 256, 256, 0, stream>>>(in_proj_w, out_proj_w, x_proj_w,
                                                       Wi_hi, Wi_lo, Wo_hi, Wo_lo, Wx_hi, Wx_lo);
    k_splitT<<<dim3(12, 32, NB), 256, 0, stream>>>(x, Ax_hi, Ax_lo, 384);
    k_gemm<384><<<dim3(12, 64), 256, 0, stream>>>(Ax_hi, Ax_lo, Wi_hi, Wi_lo, xin, szT);
    k_conv<<<dim3(24, 32, NB), 256, 0, stream>>>(xin, conv_w, conv_b, u_hi, u_lo, uT);
    k_xprojm<<<NROWS / 32, 256, 0, stream>>>(u_hi, u_lo, Wx_hi, Wx_lo, dbc, bct);
    k_dtproj<<<dim3(12, NROWS / 64), 256, 0, stream>>>(dbc, dt_proj_w, dt_proj_b, dtyT);
    k_scan<<<dim3(D_INNER, NB), 1024, 0, stream>>>(dtyT, uT, szT, bct, A_log, Dp);
    k_splitT<<<dim3(24, 32, NB), 256, 0, stream>>>(dtyT, Ay_hi, Ay_lo, 768);
    k_gemmo<<<dim3(6, 64), 256, 0, stream>>>(Ay_hi, Ay_lo, Wo_hi, Wo_lo, out);
}

// Round 14
// 284.401 us; speedup vs baseline: 1.1505x; 1.1505x over previous
//
#include <hip/hip_runtime.h>

#define D_MODEL 384
#define D_STATE 16
#define D_INNER 768
#define DT_RANK 24
#define NB 8
#define LSEQ 1024
#define NROWS (NB * LSEQ)             // 8192
#define DBC_N 56
#define SEG 16
#define NSEG 64

typedef unsigned short u16;
typedef __attribute__((ext_vector_type(8))) short bf16x8;
typedef __attribute__((ext_vector_type(4))) float f32x4;

__device__ __forceinline__ float silu(float x) { return x / (1.f + __expf(-x)); }

__device__ __forceinline__ u16 f2bf_rne(float v, float& hval) {
    unsigned u = __builtin_bit_cast(unsigned, v);
    unsigned h = (u + 0x7FFFu + ((u >> 16) & 1u)) >> 16;
    hval = __builtin_bit_cast(float, h << 16);
    return (u16)h;
}

__device__ __forceinline__ void split2(float v, u16& h, u16& l) {
    float hval, dummy;
    h = f2bf_rne(v, hval);
    l = f2bf_rne(v - hval, dummy);
}

// DPP move within rows of 16 lanes (VALU, no DS pipe). CTRL 0x120+N = row_ror:N.
template <int CTRL>
__device__ __forceinline__ float dpp_mov(float v) {
    return __builtin_bit_cast(float, __builtin_amdgcn_update_dpp(
        0, __builtin_bit_cast(int, v), CTRL, 0xf, 0xf, false));
}

// ---------------- merged weight split: in_proj + out_proj + x_proj(padded 56->64)
__global__ __launch_bounds__(256) void k_splits(const float* __restrict__ Wi,
                                                const float* __restrict__ Wo,
                                                const float* __restrict__ Wx,
                                                u16* __restrict__ Wi_hi, u16* __restrict__ Wi_lo,
                                                u16* __restrict__ Wo_hi, u16* __restrict__ Wo_lo,
                                                u16* __restrict__ Wx_hi, u16* __restrict__ Wx_lo) {
    const int NWi = 1536 * 384, NWo = 384 * 768, NWx = 64 * 768;
    const int i = blockIdx.x * 256 + threadIdx.x;
    if (i < NWi) {
        u16 h, l; split2(Wi[i], h, l);
        Wi_hi[i] = h; Wi_lo[i] = l;
    } else if (i < NWi + NWo) {
        const int j = i - NWi;
        u16 h, l; split2(Wo[j], h, l);
        Wo_hi[j] = h; Wo_lo[j] = l;
    } else if (i < NWi + NWo + NWx) {
        const int j = i - NWi - NWo;
        const int row = j / 768;
        u16 h = 0, l = 0;
        if (row < DBC_N) split2(Wx[j], h, l);
        Wx_hi[j] = h; Wx_lo[j] = l;
    }
}

// ---------------- activation split + transpose: src [B][R][1024] f32 -> hi/lo [B*1024][R] bf16
__global__ __launch_bounds__(256) void k_splitT(const float* __restrict__ src,
                                                u16* __restrict__ hi, u16* __restrict__ lo,
                                                int R) {
    __shared__ float s[32][33];
    const int r0 = blockIdx.x * 32, c0 = blockIdx.y * 32, b = blockIdx.z;
    const int t = threadIdx.x;
    const int cc = t & 31, rr = t >> 5;
#pragma unroll
    for (int p = 0; p < 4; ++p)
        s[rr + p * 8][cc] = src[((size_t)b * R + r0 + rr + p * 8) * LSEQ + c0 + cc];
    __syncthreads();
    const int rr2 = t & 31, cc2 = t >> 5;
#pragma unroll
    for (int p = 0; p < 4; ++p) {
        const int c = cc2 + p * 8;
        u16 h, l;
        split2(s[rr2][c], h, l);
        const size_t idx = ((size_t)b * LSEQ + c0 + c) * R + r0 + rr2;
        hi[idx] = h; lo[idx] = l;
    }
}

// ---------------- split-bf16 MFMA GEMM (128x128 tile), k-tile outer / 3-term inner.
// Stages A-hi/A-lo/B-hi/B-lo ONCE per k-tile (64 KB LDS), 48 MFMA per barrier pair.
// MODE 0: in_proj epilogue; MODE 1: out_proj epilogue
template <int K, int MODE>
__global__ __launch_bounds__(256) void k_gemm(const u16* __restrict__ Ahi,
                                              const u16* __restrict__ Alo,
                                              const u16* __restrict__ Bhi,
                                              const u16* __restrict__ Blo,
                                              float* __restrict__ out0,
                                              float* __restrict__ out1) {
    constexpr int KT = K / 32;
    __shared__ u16 lA[2][2][512 * 8];   // [dbuf][hi/lo]
    __shared__ u16 lB[2][2][512 * 8];
    const int tid = threadIdx.x;
    const int n0 = blockIdx.x * 128;
    const int m0 = blockIdx.y * 128;

    bf16x8 rah[2], ral[2], rbh[2], rbl[2];
    auto load_kt = [&](int kt) {
        const int ko = kt * 32;
#pragma unroll
        for (int i = 0; i < 2; ++i) {
            const int slot = tid + 256 * i;
            const size_t aoff = (size_t)(m0 + (slot & 127)) * K + ko + (slot >> 7) * 8;
            const size_t boff = (size_t)(n0 + (slot & 127)) * K + ko + (slot >> 7) * 8;
            rah[i] = *reinterpret_cast<const bf16x8*>(Ahi + aoff);
            ral[i] = *reinterpret_cast<const bf16x8*>(Alo + aoff);
            rbh[i] = *reinterpret_cast<const bf16x8*>(Bhi + boff);
            rbl[i] = *reinterpret_cast<const bf16x8*>(Blo + boff);
        }
    };
    auto write_kt = [&](int buf) {
#pragma unroll
        for (int i = 0; i < 2; ++i) {
            const int slot = tid + 256 * i;
            *reinterpret_cast<bf16x8*>(&lA[buf][0][slot * 8]) = rah[i];
            *reinterpret_cast<bf16x8*>(&lA[buf][1][slot * 8]) = ral[i];
            *reinterpret_cast<bf16x8*>(&lB[buf][0][slot * 8]) = rbh[i];
            *reinterpret_cast<bf16x8*>(&lB[buf][1][slot * 8]) = rbl[i];
        }
    };

    load_kt(0);
    write_kt(0);
    if (KT > 1) load_kt(1);

    const int lane = tid & 63, w = tid >> 6;
    const int wm = w >> 1, wn = w & 1;
    const int fr = lane & 15, g = lane >> 4;
    const int abase = (g * 128 + wm * 64 + fr) * 8;
    const int bbase = (g * 128 + wn * 64 + fr) * 8;

    f32x4 acc[4][4] = {};
    for (int kt = 0; kt < KT; ++kt) {
        const int cur = kt & 1;
        __syncthreads();
        bf16x8 ah[4], al[4], bh[4], bl[4];
#pragma unroll
        for (int mi = 0; mi < 4; ++mi) {
            ah[mi] = *reinterpret_cast<const bf16x8*>(&lA[cur][0][abase + mi * 128]);
            al[mi] = *reinterpret_cast<const bf16x8*>(&lA[cur][1][abase + mi * 128]);
        }
#pragma unroll
        for (int ni = 0; ni < 4; ++ni) {
            bh[ni] = *reinterpret_cast<const bf16x8*>(&lB[cur][0][bbase + ni * 128]);
            bl[ni] = *reinterpret_cast<const bf16x8*>(&lB[cur][1][bbase + ni * 128]);
        }
#pragma unroll
        for (int mi = 0; mi < 4; ++mi)
#pragma unroll
            for (int ni = 0; ni < 4; ++ni) {
                acc[mi][ni] = __builtin_amdgcn_mfma_f32_16x16x32_bf16(
                    ah[mi], bh[ni], acc[mi][ni], 0, 0, 0);
                acc[mi][ni] = __builtin_amdgcn_mfma_f32_16x16x32_bf16(
                    ah[mi], bl[ni], acc[mi][ni], 0, 0, 0);
                acc[mi][ni] = __builtin_amdgcn_mfma_f32_16x16x32_bf16(
                    al[mi], bh[ni], acc[mi][ni], 0, 0, 0);
            }
        if (kt + 1 < KT) {
            __syncthreads();
            write_kt(cur ^ 1);
            if (kt + 2 < KT) load_kt(kt + 2);
        }
    }

    const int b_idx = m0 >> 10;
    const int l0b = m0 & 1023;
    if (MODE == 0) {
        if (n0 < D_INNER) {
#pragma unroll
            for (int mi = 0; mi < 4; ++mi) {
#pragma unroll
                for (int ni = 0; ni < 4; ++ni) {
                    const int m = m0 + wm * 64 + mi * 16 + (lane >> 4) * 4;
                    const int n = n0 + wn * 64 + ni * 16 + (lane & 15);
#pragma unroll
                    for (int j = 0; j < 4; ++j)
                        out0[(size_t)(m + j) * D_INNER + n] = acc[mi][ni][j];
                }
            }
        } else {
#pragma unroll
            for (int mi = 0; mi < 4; ++mi) {
#pragma unroll
                for (int ni = 0; ni < 4; ++ni) {
                    const int l = l0b + wm * 64 + mi * 16 + (lane >> 4) * 4;
                    const int d = (n0 - D_INNER) + wn * 64 + ni * 16 + (lane & 15);
                    float4 v = make_float4(silu(acc[mi][ni][0]), silu(acc[mi][ni][1]),
                                           silu(acc[mi][ni][2]), silu(acc[mi][ni][3]));
                    *reinterpret_cast<float4*>(
                        &out1[((size_t)b_idx * D_INNER + d) * LSEQ + l]) = v;
                }
            }
        }
    } else {
#pragma unroll
        for (int mi = 0; mi < 4; ++mi) {
#pragma unroll
            for (int ni = 0; ni < 4; ++ni) {
                const int l = l0b + wm * 64 + mi * 16 + (lane >> 4) * 4;
                const int n = n0 + wn * 64 + ni * 16 + (lane & 15);
                float4 v = make_float4(acc[mi][ni][0], acc[mi][ni][1],
                                       acc[mi][ni][2], acc[mi][ni][3]);
                *reinterpret_cast<float4*>(
                    &out0[((size_t)b_idx * D_MODEL + n) * LSEQ + l]) = v;
            }
        }
    }
}

// ---------------- x_proj MFMA GEMM: M=8192 (64-row tiles), N=64 (padded), K=768,
// k-tile outer / 3-term inner (stages hi+lo once per k-tile).
__global__ __launch_bounds__(256) void k_xprojm(const u16* __restrict__ Uhi,
                                                const u16* __restrict__ Ulo,
                                                const u16* __restrict__ Whi,
                                                const u16* __restrict__ Wlo,
                                                float* __restrict__ dbc,
                                                float* __restrict__ bct) {
    __shared__ u16 lA[2][2][64 * 32];
    __shared__ u16 lB[2][2][64 * 32];
    const int tid = threadIdx.x;
    const int m0 = blockIdx.x * 64;
    const int arow = tid >> 2, acol = (tid & 3) * 8;

    bf16x8 rah, ral, rbh, rbl;
    auto load_kt = [&](int kt) {
        const int ko = kt * 32;
        const size_t aoff = (size_t)(m0 + arow) * D_INNER + ko + acol;
        const size_t boff = (size_t)arow * D_INNER + ko + acol;
        rah = *reinterpret_cast<const bf16x8*>(Uhi + aoff);
        ral = *reinterpret_cast<const bf16x8*>(Ulo + aoff);
        rbh = *reinterpret_cast<const bf16x8*>(Whi + boff);
        rbl = *reinterpret_cast<const bf16x8*>(Wlo + boff);
    };
    auto write_kt = [&](int buf) {
        *reinterpret_cast<bf16x8*>(&lA[buf][0][arow * 32 + acol]) = rah;
        *reinterpret_cast<bf16x8*>(&lA[buf][1][arow * 32 + acol]) = ral;
        *reinterpret_cast<bf16x8*>(&lB[buf][0][arow * 32 + acol]) = rbh;
        *reinterpret_cast<bf16x8*>(&lB[buf][1][arow * 32 + acol]) = rbl;
    };

    load_kt(0);
    write_kt(0);
    load_kt(1);

    const int lane = tid & 63, w = tid >> 6;
    const int fr = lane & 15, g = lane >> 4;
    f32x4 acc[4] = {};
    for (int kt = 0; kt < 24; ++kt) {
        const int cur = kt & 1;
        __syncthreads();
        const int af = (w * 16 + fr) * 32 + g * 8;
        bf16x8 ah = *reinterpret_cast<const bf16x8*>(&lA[cur][0][af]);
        bf16x8 al = *reinterpret_cast<const bf16x8*>(&lA[cur][1][af]);
        bf16x8 bh[4], bl[4];
#pragma unroll
        for (int ni = 0; ni < 4; ++ni) {
            const int bf = (ni * 16 + fr) * 32 + g * 8;
            bh[ni] = *reinterpret_cast<const bf16x8*>(&lB[cur][0][bf]);
            bl[ni] = *reinterpret_cast<const bf16x8*>(&lB[cur][1][bf]);
        }
#pragma unroll
        for (int ni = 0; ni < 4; ++ni) {
            acc[ni] = __builtin_amdgcn_mfma_f32_16x16x32_bf16(ah, bh[ni], acc[ni], 0, 0, 0);
            acc[ni] = __builtin_amdgcn_mfma_f32_16x16x32_bf16(ah, bl[ni], acc[ni], 0, 0, 0);
            acc[ni] = __builtin_amdgcn_mfma_f32_16x16x32_bf16(al, bh[ni], acc[ni], 0, 0, 0);
        }
        if (kt + 1 < 24) {
            __syncthreads();
            write_kt(cur ^ 1);
            if (kt + 2 < 24) load_kt(kt + 2);
        }
    }

    const int b_idx = m0 >> 10;
#pragma unroll
    for (int ni = 0; ni < 4; ++ni) {
        const int col = ni * 16 + fr;
#pragma unroll
        for (int j = 0; j < 4; ++j) {
            const int r = w * 16 + g * 4 + j;
            const float v = acc[ni][j];
            if (col < DT_RANK) {
                dbc[(size_t)(m0 + r) * DBC_N + col] = v;
            } else if (col < DBC_N) {
                bct[((size_t)b_idx * 32 + (col - DT_RANK)) * LSEQ + ((m0 & 1023) + r)] = v;
            }
        }
    }
}

// ---------------- conv (causal, 3 taps) + SiLU -> uT [b][d][l] f32 + u split bf16 row-major
__global__ __launch_bounds__(256) void k_conv(const float* __restrict__ xin,
                                              const float* __restrict__ cw,
                                              const float* __restrict__ cb,
                                              u16* __restrict__ u_hi,
                                              u16* __restrict__ u_lo,
                                              float* __restrict__ uT) {
    __shared__ float xs[34][32];
    __shared__ float us[32][33];
    const int d0 = blockIdx.x * 32;
    const int l0 = blockIdx.y * 32;
    const int b  = blockIdx.z;
    const int t = threadIdx.x;
    const int dd = t & 31, r = t >> 5;
    for (int rr = r; rr < 34; rr += 8) {
        const int l = l0 - 2 + rr;
        xs[rr][dd] = (l >= 0) ? xin[((size_t)b * LSEQ + l) * D_INNER + d0 + dd] : 0.f;
    }
    __syncthreads();
    const float w0 = cw[(d0 + dd) * 3 + 0], w1 = cw[(d0 + dd) * 3 + 1], w2 = cw[(d0 + dd) * 3 + 2];
    const float bv = cb[d0 + dd];
#pragma unroll
    for (int p = 0; p < 4; ++p) {
        const int li = r + p * 8;
        float acc = bv;
        acc = fmaf(xs[li + 0][dd], w0, acc);
        acc = fmaf(xs[li + 1][dd], w1, acc);
        acc = fmaf(xs[li + 2][dd], w2, acc);
        const float uv = silu(acc);
        u16 h, l;
        split2(uv, h, l);
        const size_t idx = ((size_t)b * LSEQ + l0 + li) * D_INNER + d0 + dd;
        u_hi[idx] = h; u_lo[idx] = l;
        us[li][dd] = uv;
    }
    __syncthreads();
    const int ll = t & 31, dg = t >> 5;
#pragma unroll
    for (int p = 0; p < 4; ++p) {
        const int dl = dg + p * 8;
        uT[((size_t)b * D_INNER + d0 + dl) * LSEQ + l0 + ll] = us[ll][dl];
    }
}

// ---------------- dt_proj (K=24) + softplus -> dtT[b][d][l] (transposed via LDS tile)
__global__ __launch_bounds__(256) void k_dtproj(const float* __restrict__ dbc,
                                                const float* __restrict__ W,
                                                const float* __restrict__ bias,
                                                float* __restrict__ dtT) {
    __shared__ float sd[64][25];
    __shared__ float sw[64][24];
    __shared__ float sb[64];
    const int d0 = blockIdx.x * 64;
    const int row0 = blockIdx.y * 64;
    const int b = row0 >> 10, lr0 = row0 & 1023;
    const int t = threadIdx.x;
    for (int e = t; e < 64 * 24; e += 256) {
        const int rl = e / 24, rr = e - rl * 24;
        sd[rl][rr] = dbc[(size_t)(row0 + rl) * DBC_N + rr];
        sw[rl][rr] = W[(size_t)(d0 + rl) * DT_RANK + rr];
    }
    if (t < 64) sb[t] = bias[d0 + t];
    __syncthreads();
    const int ll = t & 63, dg = t >> 6;
    for (int dd = 0; dd < 16; ++dd) {
        const int dl = dg * 16 + dd;
        float acc = sb[dl];
#pragma unroll
        for (int r = 0; r < DT_RANK; ++r) acc = fmaf(sd[ll][r], sw[dl][r], acc);
        const float v = (acc > 20.f) ? acc : log1pf(__expf(acc));
        dtT[((size_t)b * D_INNER + d0 + dl) * LSEQ + lr0 + ll] = v;
    }
}

// ---------------- block-parallel selective scan (v3, measured 108 us).
// Pass A: per-segment (P,H). Segment scan: IN-WAVE (wave w scans the 64
// segments of state n=w via shfl_up, no barriers). Pass C: n-reduction via
// DPP row_ror rotate-reduce (pure VALU, zero DS ops). 4 barriers total.
__global__ __launch_bounds__(1024, 8) void k_scan(float* dtyT,
                                                  const float* __restrict__ uT,
                                                  const float* __restrict__ szT,
                                                  const float* __restrict__ bct,
                                                  const float* __restrict__ A_log,
                                                  const float* __restrict__ Dp) {
    __shared__ float dt_s[LSEQ], u_s[LSEQ], sz_s[LSEQ], y_s[LSEQ];
    __shared__ float Pb[16][NSEG + 2], Hb[16][NSEG + 2];
    const int t = threadIdx.x;
    const int d = blockIdx.x;
    const int b = blockIdx.y;
    const size_t base = ((size_t)b * D_INNER + d) * LSEQ;
    if (t < 256) {
        *reinterpret_cast<float4*>(&dt_s[t * 4]) =
            *reinterpret_cast<const float4*>(&dtyT[base + t * 4]);
    } else if (t < 512) {
        const int q = (t - 256) * 4;
        *reinterpret_cast<float4*>(&u_s[q]) = *reinterpret_cast<const float4*>(&uT[base + q]);
    } else if (t < 768) {
        const int q = (t - 512) * 4;
        *reinterpret_cast<float4*>(&sz_s[q]) = *reinterpret_cast<const float4*>(&szT[base + q]);
    }
    const int n = t & 15, seg = t >> 4;
    const float Aval = -__expf(A_log[d * D_STATE + n]);
    const float Dv = Dp[d];
    float Breg[SEG];
    {
        const size_t bb = ((size_t)b * 32 + n) * LSEQ + seg * SEG;
#pragma unroll
        for (int q = 0; q < SEG; q += 4)
            *reinterpret_cast<float4*>(&Breg[q]) = *reinterpret_cast<const float4*>(&bct[bb + q]);
    }
    __syncthreads();
    const int l0 = seg * SEG;
    // pass A: segment-local transform (P, H)
    float h = 0.f, P = 1.f;
#pragma unroll
    for (int l = 0; l < SEG; ++l) {
        const float dtv = dt_s[l0 + l];
        const float a = __expf(dtv * Aval);
        h = fmaf(a, h, dtv * u_s[l0 + l] * Breg[l]);
        P *= a;
    }
    Pb[n][seg] = P;
    Hb[n][seg] = h;
    // deferred Creg load: latency hides under the scan phase below
    float Creg[SEG];
    {
        const size_t cc = ((size_t)b * 32 + 16 + n) * LSEQ + seg * SEG;
#pragma unroll
        for (int q = 0; q < SEG; q += 4)
            *reinterpret_cast<float4*>(&Creg[q]) = *reinterpret_cast<const float4*>(&bct[cc + q]);
    }
    __syncthreads();
    // in-wave inclusive scan: wave w owns state n=w, lane = segment index
    {
        const int w = t >> 6, lane = t & 63;
        float Pw = Pb[w][lane], Hw = Hb[w][lane];
#pragma unroll
        for (int off = 1; off < NSEG; off <<= 1) {
            const float Pp = __shfl_up(Pw, off);
            const float Hp = __shfl_up(Hw, off);
            if (lane >= off) {
                Hw = fmaf(Hp, Pw, Hw);
                Pw *= Pp;
            }
        }
        Hb[w][lane] = Hw;
    }
    __syncthreads();
    // pass C: exact prefix; n-reduce via DPP rotate within rows of 16
    h = (seg == 0) ? 0.f : Hb[n][seg - 1];
#pragma unroll
    for (int l = 0; l < SEG; ++l) {
        const float dtv = dt_s[l0 + l];
        const float u_v = u_s[l0 + l];
        const float a = __expf(dtv * Aval);
        h = fmaf(a, h, dtv * u_v * Breg[l]);
        float p = h * Creg[l];
        p += dpp_mov<0x128>(p);   // row_ror:8
        p += dpp_mov<0x124>(p);   // row_ror:4
        p += dpp_mov<0x122>(p);   // row_ror:2
        p += dpp_mov<0x121>(p);   // row_ror:1
        if (n == 0)
            y_s[l0 + l] = fmaf(u_v, Dv, p) * sz_s[l0 + l];
    }
    __syncthreads();
    if (t < 256)
        *reinterpret_cast<float4*>(&dtyT[base + t * 4]) =
            *reinterpret_cast<const float4*>(&y_s[t * 4]);
}

extern "C" void kernel_launch(void* const* d_in, const int* in_sizes, int n_in,
                              void* d_out, int out_size, void* d_ws, size_t ws_size,
                              hipStream_t stream) {
    const float* x         = (const float*)d_in[0];
    const float* in_proj_w = (const float*)d_in[1];
    const float* conv_w    = (const float*)d_in[2];
    const float* conv_b    = (const float*)d_in[3];
    const float* x_proj_w  = (const float*)d_in[4];
    const float* dt_proj_w = (const float*)d_in[5];
    const float* dt_proj_b = (const float*)d_in[6];
    const float* A_log     = (const float*)d_in[7];
    const float* Dp        = (const float*)d_in[8];
    const float* out_proj_w= (const float*)d_in[9];
    float* out = (float*)d_out;

    const size_t SB = (size_t)NROWS * D_INNER * 4;   // 25.2 MB
    char* wsb = (char*)d_ws;
    float* xin   = (float*)(wsb);                    // R0: xin, then dtT/y
    float* szT   = (float*)(wsb + SB);               // R1
    u16*  u_hi   = (u16*)  (wsb + 2 * SB);           // R2: u split bf16
    u16*  u_lo   = u_hi + (size_t)NROWS * D_INNER;
    float* uT    = (float*)(wsb + 3 * SB);           // R3: Ax split, then uT, then Ay split
    float* dbc   = (float*)(wsb + 4 * SB);
    float* bct   = (float*)(wsb + 4 * SB + 1835008);
    u16*  Wi_hi  = (u16*) (wsb + 4 * SB + 1835008 + 1048576);
    u16*  Wi_lo  = Wi_hi + 1536 * 384;
    u16*  Wo_hi  = Wi_lo + 1536 * 384;
    u16*  Wo_lo  = Wo_hi + 384 * 768;
    u16*  Wx_hi  = Wo_lo + 384 * 768;
    u16*  Wx_lo  = Wx_hi + 64 * 768;
    u16*  Ax_hi  = (u16*)uT;                 // dead before conv writes uT
    u16*  Ax_lo  = Ax_hi + (size_t)NROWS * 384;
    u16*  Ay_hi  = (u16*)uT;                 // uT dead after scan
    u16*  Ay_lo  = Ay_hi + (size_t)NROWS * 768;
    float* dtyT  = xin;                      // xin dead after conv; dt then y in place

    const int NSPLIT = 1536 * 384 + 384 * 768 + 64 * 768;
    k_splits<<<(NSPLIT + 255) / 256, 256, 0, stream>>>(in_proj_w, out_proj_w, x_proj_w,
                                                       Wi_hi, Wi_lo, Wo_hi, Wo_lo, Wx_hi, Wx_lo);
    k_splitT<<<dim3(12, 32, NB), 256, 0, stream>>>(x, Ax_hi, Ax_lo, 384);
    k_gemm<384, 0><<<dim3(12, 64), 256, 0, stream>>>(Ax_hi, Ax_lo, Wi_hi, Wi_lo, xin, szT);
    k_conv<<<dim3(24, 32, NB), 256, 0, stream>>>(xin, conv_w, conv_b, u_hi, u_lo, uT);
    k_xprojm<<<NROWS / 64, 256, 0, stream>>>(u_hi, u_lo, Wx_hi, Wx_lo, dbc, bct);
    k_dtproj<<<dim3(12, NROWS / 64), 256, 0, stream>>>(dbc, dt_proj_w, dt_proj_b, dtyT);
    k_scan<<<dim3(D_INNER, NB), 1024, 0, stream>>>(dtyT, uT, szT, bct, A_log, Dp);
    k_splitT<<<dim3(24, 32, NB), 256, 0, stream>>>(dtyT, Ay_hi, Ay_lo, 768);
    k_gemm<768, 1><<<dim3(3, 64), 256, 0, stream>>>(Ay_hi, Ay_lo, Wo_hi, Wo_lo, out, nullptr);
}